// Round 3
// baseline (426.949 us; speedup 1.0000x reference)
//
#include <hip/hip_runtime.h>
#include <hip/hip_bf16.h>

typedef unsigned short u16;
typedef unsigned int   u32;
typedef short  s16x8 __attribute__((ext_vector_type(8)));
typedef __bf16 bf16x8 __attribute__((ext_vector_type(8)));
typedef float  f32x4 __attribute__((ext_vector_type(4)));

#define D_ 512
#define NR 33344          // B*L*M + B*72 = 32768 + 576
#define NRP 33536         // padded to 131*256 (BM=256)
#define TROWS 32768       // temp rows
#define TOUT_OFF  0UL
#define OOUT_OFF  16809984UL
#define TATTN_OFF 17072128UL
#define OATTN_OFF 35946496UL

__device__ __forceinline__ float bf2f(u16 x) {
    union { u32 u; float f; } v; v.u = ((u32)x) << 16; return v.f;
}
__device__ __forceinline__ u16 f2bf(float f) {
    union { float f; u32 u; } v; v.f = f;
    u32 u = v.u;
    return (u16)((u + 0x7fffu + ((u >> 16) & 1u)) >> 16);
}
// load 8 contiguous fp32, round-to-nearest-even to bf16x8
__device__ __forceinline__ s16x8 cvt8(const float* p) {
    float4 a = *(const float4*)p;
    float4 b = *(const float4*)(p + 4);
    s16x8 r;
    r[0] = (short)f2bf(a.x); r[1] = (short)f2bf(a.y);
    r[2] = (short)f2bf(a.z); r[3] = (short)f2bf(a.w);
    r[4] = (short)f2bf(b.x); r[5] = (short)f2bf(b.y);
    r[6] = (short)f2bf(b.z); r[7] = (short)f2bf(b.w);
    return r;
}
__device__ __forceinline__ f32x4 mfma16(s16x8 a, s16x8 b, f32x4 c) {
    return __builtin_amdgcn_mfma_f32_16x16x32_bf16(
        __builtin_bit_cast(bf16x8, a), __builtin_bit_cast(bf16x8, b), c, 0, 0, 0);
}
__device__ __forceinline__ void gload_lds16(const u16* g, u16* l) {
    __builtin_amdgcn_global_load_lds(
        (const __attribute__((address_space(1))) void*)g,
        (__attribute__((address_space(3))) void*)l, 16, 0, 0);
}

// row r of the fused A matrix -> source row pointer (fp32)
__device__ __forceinline__ const float* a_src_row(int r, const float* temporal, const float* others) {
    if (r < TROWS) {
        int b = r >> 12;
        return temporal + (size_t)(r + 8 * (b + 1)) * D_;
    }
    int rr = r - TROWS;
    int b = rr / 72, j = rr - b * 72;
    return (j < 8) ? (temporal + (size_t)(b * 4104 + j) * D_)
                   : (others   + (size_t)(b * 64 + j - 8) * D_);
}

// ---------------- pre-pass: fp32 -> bf16, A in GEMM row order + W concat ----------------
__global__ __launch_bounds__(256) void prep_4715(
    const float* __restrict__ temporal, const float* __restrict__ others,
    const float* __restrict__ Wq, const float* __restrict__ Wk, const float* __restrict__ Wv,
    u16* __restrict__ Ab, u16* __restrict__ Wb)
{
    int idx = blockIdx.x * 256 + threadIdx.x;   // one thread = 8 floats
    int r  = idx >> 6;
    int ch = (idx & 63) * 8;
    if (r >= NRP + 1536) return;
    if (r < NRP) {
        u16* dst = Ab + (size_t)r * D_ + ch;
        if (r >= NR) {                           // zero pad rows
            u32* d32 = (u32*)dst;
            d32[0] = 0; d32[1] = 0; d32[2] = 0; d32[3] = 0;
            return;
        }
        *(s16x8*)dst = cvt8(a_src_row(r, temporal, others) + ch);
    } else {
        int n = r - NRP;
        const float* W = (n < 512) ? Wq : (n < 1024 ? Wk : Wv);
        *(s16x8*)(Wb + (size_t)n * D_ + ch) = cvt8(W + (size_t)(n & 511) * D_ + ch);
    }
}

// ---------------- QKV GEMM: 256x256 tile, 8-phase schedule (T3+T4+T2+T5+T1) ----------------
// Per K-tile: 4 phases = 4 C-quadrants x 16 MFMA. Each phase stages exactly ONE half-tile
// (128 rows x 64 cols, 2 global_load_lds per wave). vmcnt(6) only at phases 4/8 (3 half-tiles
// in flight across barriers, never drained in main loop). Region lifetimes: B(buf) dies after
// p1 (all B frags read at p1), A(buf) after p3 -> stage stream B0@p2,B1@p3,A0@p4,A1@p5
// targets only dead regions. XOR-swizzle on global source + swizzled ds_read (conflicts=0).
__global__ __launch_bounds__(512, 2) void qkv_gemm2_4715(
    const u16* __restrict__ Ab, const u16* __restrict__ Wb,
    const float* __restrict__ bq, const float* __restrict__ bk, const float* __restrict__ bv,
    u16* __restrict__ Qb, u16* __restrict__ Kb, u16* __restrict__ Vb)
{
    __shared__ __align__(16) u16 As[2][256][64];   // 64 KB (buf x rows x K64)
    __shared__ __align__(16) u16 Bs[2][256][64];   // 64 KB  (total 128 KB -> 1 block/CU)
    const int tid  = threadIdx.x;
    const int lane = tid & 63;
    const int w    = tid >> 6;                // 8 waves
    const int wr = w >> 2, wc = w & 3;        // 2 x 4 wave grid, each wave 128x64 output

    // bijective XCD swizzle (m204): 786 blocks = 8*98 + 2
    const int NB  = 131 * 6;
    const int qch = NB >> 3, rch = NB & 7;    // 98, 2
    int orig = blockIdx.x;
    int xcd = orig & 7, lid = orig >> 3;
    int gx = (xcd < rch ? xcd * (qch + 1) : rch * (qch + 1) + (xcd - rch) * qch) + lid;
    const int nblk = gx % 6;                  // n fastest: 6 consecutive work ids share A-panel
    const int mblk = gx / 6;
    const int m0 = mblk * 256, n0 = nblk * 256;

    // staging: per half-tile, wave w covers rows w*16 .. w*16+15 (2 calls x 8 rows).
    // LDS dest linear; swizzle on GLOBAL source granule: LDS[r][g] = global[r][g ^ (r&7)].
    const int swzg = ((lane & 7) ^ ((lane >> 3) & 7)) * 8;   // u16 elements
    const int ldr  = lane >> 3;

    const int fr = lane & 15;
    const int q  = lane >> 4;

    f32x4 acc[8][4];
    #pragma unroll
    for (int i = 0; i < 8; ++i)
        #pragma unroll
        for (int j = 0; j < 4; ++j) acc[i][j] = f32x4{0.f, 0.f, 0.f, 0.f};

    s16x8 Areg[4][2];   // current m-half: 4 m-frags x 2 ksteps
    s16x8 Breg[4][2];   // all 4 n-frags x 2 ksteps (held for the whole K-tile)

#define STG_A(buf, h, t) {                                                          \
    _Pragma("unroll")                                                               \
    for (int cc = 0; cc < 2; ++cc)                                                  \
        gload_lds16(Ab + (size_t)(m0 + (h) * 128 + w * 16 + cc * 8 + ldr) * D_      \
                       + (t) * 64 + swzg,                                           \
                    &As[buf][(h) * 128 + w * 16 + cc * 8][0]); }
#define STG_B(buf, h, t) {                                                          \
    _Pragma("unroll")                                                               \
    for (int cc = 0; cc < 2; ++cc)                                                  \
        gload_lds16(Wb + (size_t)(n0 + (h) * 128 + w * 16 + cc * 8 + ldr) * D_      \
                       + (t) * 64 + swzg,                                           \
                    &Bs[buf][(h) * 128 + w * 16 + cc * 8][0]); }

    // physical granule = logical(ks*4+q) ^ (row&7); row&7 == fr&7 for all fragment rows
#define COLO(ks) ((((ks) * 4 + q) ^ (fr & 7)) * 8)
#define READ_A(buf, mh) {                                                           \
    _Pragma("unroll")                                                               \
    for (int mi = 0; mi < 4; ++mi)                                                  \
        _Pragma("unroll")                                                           \
        for (int ks = 0; ks < 2; ++ks)                                              \
            Areg[mi][ks] = *(const s16x8*)                                          \
                &As[buf][wr * 128 + ((mh) * 4 + mi) * 16 + fr][COLO(ks)]; }
#define READ_B(buf) {                                                               \
    _Pragma("unroll")                                                               \
    for (int nj = 0; nj < 4; ++nj)                                                  \
        _Pragma("unroll")                                                           \
        for (int ks = 0; ks < 2; ++ks)                                              \
            Breg[nj][ks] = *(const s16x8*)                                          \
                &Bs[buf][wc * 64 + nj * 16 + fr][COLO(ks)]; }

#define MMA_Q(mh, nh) {                                                             \
    __builtin_amdgcn_s_setprio(1);                                                  \
    _Pragma("unroll")                                                               \
    for (int ks = 0; ks < 2; ++ks)                                                  \
        _Pragma("unroll")                                                           \
        for (int mi = 0; mi < 4; ++mi)                                              \
            _Pragma("unroll")                                                       \
            for (int nj = 0; nj < 2; ++nj)                                          \
                acc[(mh) * 4 + mi][(nh) * 2 + nj] =                                 \
                    mfma16(Areg[mi][ks], Breg[(nh) * 2 + nj][ks],                   \
                           acc[(mh) * 4 + mi][(nh) * 2 + nj]);                      \
    __builtin_amdgcn_s_setprio(0); }

#define BAR() { __builtin_amdgcn_sched_barrier(0); __builtin_amdgcn_s_barrier();    \
                __builtin_amdgcn_sched_barrier(0); }
#define LGKM0() { asm volatile("s_waitcnt lgkmcnt(0)" ::: "memory");                \
                  __builtin_amdgcn_sched_barrier(0); }
#define VMC(n) { asm volatile("s_waitcnt vmcnt(" #n ")" ::: "memory");              \
                 __builtin_amdgcn_sched_barrier(0); }

    // ---- prologue: t0 fully + t1 {B0,B1,A0}; leave t1's 3 halves in flight ----
    STG_B(0, 0, 0) STG_B(0, 1, 0) STG_A(0, 0, 0) STG_A(0, 1, 0)
    STG_B(1, 0, 1) STG_B(1, 1, 1) STG_A(1, 0, 1)
    VMC(6)                                   // t0 landed (in-order retirement)
    BAR()

    // ---- main loop: iteration i computes tiles 2i (buf0) and 2i+1 (buf1) ----
    #pragma unroll
    for (int i = 0; i < 4; ++i) {
        const int tb = 2 * i + 1, tc = 2 * i + 2, td = 2 * i + 3;
        const bool st = (i < 3);
        // p1: reads t(2i) A-half0 + all B; stage t(2i+1).A1 -> buf1.A1 (dead since prev p7)
        READ_A(0, 0) READ_B(0)
        STG_A(1, 1, tb)
        BAR() LGKM0()
        MMA_Q(0, 0)
        BAR()
        // p2: stage tc.B0 -> buf0.B0 (dead after p1)
        if (st) STG_B(0, 0, tc)
        BAR()
        MMA_Q(0, 1)
        BAR()
        // p3: reads t(2i) A-half1; stage tc.B1 -> buf0.B1 (dead after p1)
        READ_A(0, 1)
        if (st) STG_B(0, 1, tc)
        BAR() LGKM0()
        MMA_Q(1, 0)
        BAR()
        // p4: stage tc.A0 -> buf0.A0 (dead after p3); tile boundary vmcnt
        if (st) STG_A(0, 0, tc)
        BAR()
        MMA_Q(1, 1)
        if (st) { VMC(6) } else { VMC(0) }   // t(2i+1) fully landed
        BAR()
        // p5: reads t(2i+1) A-half0 + all B (buf1); stage tc.A1 -> buf0.A1 (dead after p3)
        READ_A(1, 0) READ_B(1)
        if (st) STG_A(0, 1, tc)
        BAR() LGKM0()
        MMA_Q(0, 0)
        BAR()
        // p6: stage td.B0 -> buf1.B0 (dead after p5)
        if (st) STG_B(1, 0, td)
        BAR()
        MMA_Q(0, 1)
        BAR()
        // p7: reads t(2i+1) A-half1; stage td.B1 -> buf1.B1 (dead after p5)
        READ_A(1, 1)
        if (st) STG_B(1, 1, td)
        BAR() LGKM0()
        MMA_Q(1, 0)
        BAR()
        // p8: stage td.A0 -> buf1.A0 (dead after p7); tile boundary vmcnt
        if (st) STG_A(1, 0, td)
        BAR()
        MMA_Q(1, 1)
        if (st) { VMC(6) }                   // t(2i+2) fully landed for next p1
        BAR()
    }

#undef STG_A
#undef STG_B
#undef COLO
#undef READ_A
#undef READ_B
#undef MMA_Q
#undef BAR
#undef LGKM0
#undef VMC

    const int c = lane & 15;
    #pragma unroll
    for (int j = 0; j < 4; ++j) {
        int n = n0 + wc * 64 + j * 16 + c;
        u16* outp          = (n < 512) ? Qb : (n < 1024 ? Kb : Vb);
        const float* biasp = (n < 512) ? bq : (n < 1024 ? bk : bv);
        int nn = n & 511;
        float bias = biasp[nn];
        #pragma unroll
        for (int i = 0; i < 8; ++i) {
            int rb = m0 + wr * 128 + i * 16 + q * 4;
            #pragma unroll
            for (int p = 0; p < 4; ++p) {
                int r = rb + p;
                if (r < NR) outp[(size_t)r * D_ + nn] = f2bf(acc[i][j][p] + bias);
            }
        }
    }
}

// ---------------- fallback fused QKV GEMM (fp32 in, cvt in staging) ----------------
__global__ __launch_bounds__(256) void qkv_gemm_4715(
    const float* __restrict__ temporal, const float* __restrict__ others,
    const float* __restrict__ Wq, const float* __restrict__ bq,
    const float* __restrict__ Wk, const float* __restrict__ bk,
    const float* __restrict__ Wv, const float* __restrict__ bv,
    u16* __restrict__ Qb, u16* __restrict__ Kb, u16* __restrict__ Vb)
{
    __shared__ __align__(16) u16 As[128][72];
    __shared__ __align__(16) u16 Bs[128][72];
    const int tid  = threadIdx.x;
    const int lane = tid & 63;
    const int wave = tid >> 6;
    const int wr = wave >> 1, wc = wave & 1;
    const int m0 = blockIdx.x * 128;
    const int n0 = blockIdx.y * 128;

    const float* arow[4];
    #pragma unroll
    for (int i = 0; i < 4; ++i) {
        int r = m0 + (tid >> 3) + i * 32;
        if (r >= NR) r = 0;
        arow[i] = a_src_row(r, temporal, others);
    }
    const float* brow[4];
    #pragma unroll
    for (int i = 0; i < 4; ++i) {
        int n = n0 + (tid >> 3) + i * 32;
        const float* W = (n < 512) ? Wq : (n < 1024 ? Wk : Wv);
        brow[i] = W + (size_t)(n & 511) * D_;
    }
    const int acol = (tid & 7) * 8;
    const int srow = tid >> 3;

    f32x4 acc[4][4];
    #pragma unroll
    for (int i = 0; i < 4; ++i)
        #pragma unroll
        for (int j = 0; j < 4; ++j) acc[i][j] = f32x4{0.f, 0.f, 0.f, 0.f};

    for (int k0 = 0; k0 < 512; k0 += 64) {
        #pragma unroll
        for (int i = 0; i < 4; ++i) {
            *(s16x8*)&As[srow + i * 32][acol] = cvt8(arow[i] + k0 + acol);
            *(s16x8*)&Bs[srow + i * 32][acol] = cvt8(brow[i] + k0 + acol);
        }
        __syncthreads();
        #pragma unroll
        for (int kk = 0; kk < 64; kk += 32) {
            const int kc = kk + (lane >> 4) * 8;
            const int fr = lane & 15;
            s16x8 af[4], bfr[4];
            #pragma unroll
            for (int i = 0; i < 4; ++i) af[i]  = *(const s16x8*)&As[wr * 64 + i * 16 + fr][kc];
            #pragma unroll
            for (int j = 0; j < 4; ++j) bfr[j] = *(const s16x8*)&Bs[wc * 64 + j * 16 + fr][kc];
            #pragma unroll
            for (int i = 0; i < 4; ++i)
                #pragma unroll
                for (int j = 0; j < 4; ++j)
                    acc[i][j] = mfma16(af[i], bfr[j], acc[i][j]);
        }
        __syncthreads();
    }
    const int q = lane >> 4, c = lane & 15;
    #pragma unroll
    for (int j = 0; j < 4; ++j) {
        int n = n0 + wc * 64 + j * 16 + c;
        u16* outp          = (n < 512) ? Qb : (n < 1024 ? Kb : Vb);
        const float* biasp = (n < 512) ? bq : (n < 1024 ? bk : bv);
        int nn = n & 511;
        float bias = biasp[nn];
        #pragma unroll
        for (int i = 0; i < 4; ++i) {
            int rb = m0 + wr * 64 + i * 16 + q * 4;
            #pragma unroll
            for (int p = 0; p < 4; ++p) {
                int r = rb + p;
                if (r < NR) outp[(size_t)r * D_ + nn] = f2bf(acc[i][j][p] + bias);
            }
        }
    }
}

// ---------------- temporal attention (MFMA, M padded 8->16, N padded 72->80/96) ----------------
__global__ __launch_bounds__(256) void temporal_attn_4715(
    const u16* __restrict__ Qb, const u16* __restrict__ Kb, const u16* __restrict__ Vb,
    float* __restrict__ out)
{
    const int blk = blockIdx.x;           // ((b*4 + hp)*32 + lc)
    const int lc = blk & 31;
    const int hp = (blk >> 5) & 3;
    const int b  = blk >> 7;
    const int tid = threadIdx.x, lane = tid & 63, w = tid >> 6;
    const int q = lane >> 4, c = lane & 15;

    __shared__ __align__(16) u16 KtsS[2][64][72];   // cross-wave, written once
    __shared__ __align__(16) u16 VtsS[2][64][96];   // cross-wave, written once
    __shared__ __align__(16) u16 KttW[4][8][72];    // wave-private
    __shared__ __align__(16) u16 VttW[4][64][8];    // wave-private
    __shared__ __align__(16) u16 Pw[4][16][104];    // wave-private (pad cols written once)

    const size_t srowbase = (size_t)TROWS + (size_t)b * 72 + 8;
    for (int cch = tid; cch < 1024; cch += 256) {
        int hh = cch >> 9;
        int o  = (cch >> 3) & 63;
        int d8 = (cch & 7) * 8;
        int hbase = (hp * 2 + hh) * 64;
        *(s16x8*)&KtsS[hh][o][d8] = *(const s16x8*)&Kb[(srowbase + o) * D_ + hbase + d8];
        s16x8 vv = *(const s16x8*)&Vb[(srowbase + o) * D_ + hbase + d8];
        #pragma unroll
        for (int jj = 0; jj < 8; ++jj) VtsS[hh][d8 + jj][8 + o] = (u16)vv[jj];
    }
    for (int z = tid; z < 2 * 64 * 24; z += 256) {
        int hh = z / (64 * 24); int rem = z - hh * 64 * 24;
        VtsS[hh][rem / 24][72 + rem % 24] = 0;
    }
    for (int z = tid; z < 4 * 16 * 24; z += 256) {
        int ww = z / (16 * 24); int rem = z - ww * 16 * 24;
        Pw[ww][rem / 24][80 + rem % 24] = 0;
    }
    __syncthreads();    // the ONLY barrier: everything below is wave-private

    const float scale = 0.125f;
    for (int ti = 0; ti < 8; ++ti) {
        const int tsk = w + 4 * ti;               // 0..31
        const int hh = tsk >> 4;
        const int il = tsk & 15;
        const int l  = lc * 16 + il;
        const int h  = hp * 2 + hh;
        const int hbase = h * 64;
        const size_t rbase = ((size_t)b * 512 + l) * 8;

        { // stage Ktt (8x64) for this wave
            int m = lane >> 3, d8 = (lane & 7) * 8;
            *(s16x8*)&KttW[w][m][d8] = *(const s16x8*)&Kb[(rbase + m) * D_ + hbase + d8];
        }
        { // stage Vtt^T (64 x 8)
            #pragma unroll
            for (int m = 0; m < 8; ++m)
                VttW[w][lane][m] = Vb[(rbase + m) * D_ + hbase + lane];
        }
        const int mq = (c < 8) ? c : (c - 8);
        s16x8 aq0 = *(const s16x8*)&Qb[(rbase + mq) * D_ + hbase + q * 8];
        s16x8 aq1 = *(const s16x8*)&Qb[(rbase + mq) * D_ + hbase + 32 + q * 8];
        asm volatile("s_waitcnt lgkmcnt(0)" ::: "memory");  // in-wave RAW on KttW/VttW

        // QK^T: 5 n-tiles of 16, k = 64 (2 steps)
        f32x4 sacc[5];
        #pragma unroll
        for (int j = 0; j < 5; ++j) sacc[j] = f32x4{0.f, 0.f, 0.f, 0.f};
        #pragma unroll
        for (int j = 0; j < 5; ++j) {
            int g = j * 16 + c;
            const u16* kp0;
            if (g < 8) kp0 = &KttW[w][g][0];
            else { int o = g - 8; if (o > 63) o = 63; kp0 = &KtsS[hh][o][0]; }
            s16x8 b0 = *(const s16x8*)(kp0 + q * 8);
            s16x8 b1 = *(const s16x8*)(kp0 + 32 + q * 8);
            sacc[j] = mfma16(aq0, b0, sacc[j]);
            sacc[j] = mfma16(aq1, b1, sacc[j]);
        }
        float ev[5][4];
        float mx[4] = {-1e30f, -1e30f, -1e30f, -1e30f};
        #pragma unroll
        for (int j = 0; j < 5; ++j) {
            bool valid = (j < 4) || (c < 8);
            #pragma unroll
            for (int p = 0; p < 4; ++p) {
                float v = sacc[j][p] * scale;
                ev[j][p] = valid ? v : -1e30f;
                if (valid) mx[p] = fmaxf(mx[p], v);
            }
        }
        #pragma unroll
        for (int msk = 1; msk < 16; msk <<= 1)
            #pragma unroll
            for (int p = 0; p < 4; ++p)
                mx[p] = fmaxf(mx[p], __shfl_xor(mx[p], msk, 16));
        float sm[4] = {0.f, 0.f, 0.f, 0.f};
        #pragma unroll
        for (int j = 0; j < 5; ++j) {
            bool valid = (j < 4) || (c < 8);
            #pragma unroll
            for (int p = 0; p < 4; ++p) {
                float e = valid ? __expf(ev[j][p] - mx[p]) : 0.f;
                ev[j][p] = e;
                sm[p] += e;
            }
        }
        #pragma unroll
        for (int msk = 1; msk < 16; msk <<= 1)
            #pragma unroll
            for (int p = 0; p < 4; ++p)
                sm[p] += __shfl_xor(sm[p], msk, 16);
        float inv[4];
        #pragma unroll
        for (int p = 0; p < 4; ++p) inv[p] = 1.0f / sm[p];

        float* attnp = out + TATTN_OFF + ((((size_t)b * 8 + h) * 512 + l) * 8) * 72;
        #pragma unroll
        for (int j = 0; j < 5; ++j) {
            #pragma unroll
            for (int p = 0; p < 4; ++p) {
                int row = q * 4 + p;
                int col = j * 16 + c;
                float pv = ev[j][p] * inv[p];
                Pw[w][row][col] = f2bf(pv);
                if (row < 8 && col < 72)
                    attnp[(size_t)row * 72 + col] = pv;
            }
        }
        asm volatile("s_waitcnt lgkmcnt(0)" ::: "memory");  // in-wave RAW on Pw

        f32x4 oacc[4];
        #pragma unroll
        for (int j = 0; j < 4; ++j) oacc[j] = f32x4{0.f, 0.f, 0.f, 0.f};
        #pragma unroll
        for (int ks = 0; ks < 3; ++ks) {
            s16x8 ap = *(const s16x8*)&Pw[w][c][ks * 32 + q * 8];
            #pragma unroll
            for (int j = 0; j < 4; ++j) {
                int d = j * 16 + c;
                int kb = ks * 32 + q * 8;
                const u16* vp = (kb == 0) ? &VttW[w][d][0] : &VtsS[hh][d][kb];
                s16x8 bp = *(const s16x8*)vp;
                oacc[j] = mfma16(ap, bp, oacc[j]);
            }
        }
        float* toutp = out + (((size_t)b * 513 + l + 1) * 8) * 512 + hbase;
        #pragma unroll
        for (int j = 0; j < 4; ++j) {
            int d = j * 16 + c;
            #pragma unroll
            for (int p = 0; p < 4; ++p) {
                int row = q * 4 + p;
                if (row < 8)
                    toutp[(size_t)row * 512 + d] = oacc[j][p];
            }
        }
    }
}

// ---------------- others (ss) attention ----------------
__global__ __launch_bounds__(256) void others_attn_4715(
    const u16* __restrict__ Qb, const u16* __restrict__ Kb, const u16* __restrict__ Vb,
    float* __restrict__ out)
{
    const int blk = blockIdx.x;       // ((b*8 + h)*4 + mq)
    const int mq = blk & 3;
    const int h  = (blk >> 2) & 7;
    const int b  = blk >> 5;
    const int tid = threadIdx.x;
    const int hbase = h * 64;
    const size_t rbase = (size_t)TROWS + (size_t)b * 72;

    __shared__ float Qo[18][68];
    __shared__ float Ko[72][68];
    __shared__ float VoT[64][84];
    __shared__ float S[18][80];

    for (int e = tid; e < 72 * 64; e += 256) {
        int r = e >> 6, d = e & 63;
        Ko[r][d]  = bf2f(Kb[(rbase + r) * D_ + hbase + d]);
        VoT[d][r] = bf2f(Vb[(rbase + r) * D_ + hbase + d]);
    }
    for (int e = tid; e < 18 * 64; e += 256) {
        int r = e >> 6, d = e & 63;
        Qo[r][d] = bf2f(Qb[(rbase + mq * 18 + r) * D_ + hbase + d]);
    }
    for (int e = tid; e < 64 * 12; e += 256) VoT[e / 12][72 + e % 12] = 0.f;
    __syncthreads();

    for (int e = tid; e < 18 * 72; e += 256) {
        int m = e / 72, n = e - m * 72;
        const float* qp = Qo[m];
        const float* kp = Ko[n];
        float s = 0.f;
        #pragma unroll
        for (int d = 0; d < 64; ++d) s += qp[d] * kp[d];
        S[m][n] = s * 0.125f;
    }
    __syncthreads();
    if (tid < 18) {
        int m = tid;
        float mx = -1e30f;
        for (int n = 0; n < 72; ++n) mx = fmaxf(mx, S[m][n]);
        float sm = 0.f;
        for (int n = 0; n < 72; ++n) { float e = __expf(S[m][n] - mx); S[m][n] = e; sm += e; }
        float inv = 1.f / sm;
        size_t arow = OATTN_OFF + (((size_t)b * 8 + h) * 72 + (mq * 18 + m)) * 72;
        for (int n = 0; n < 72; ++n) {
            float p = S[m][n] * inv; S[m][n] = p;
            out[arow + n] = p;
        }
    }
    __syncthreads();
    // others_ = others.reshape(B,-1,D), no transpose: (h,n,d) -> i=h*9+n/8, j=(n%8)*64+d
    for (int e = tid; e < 18 * 64; e += 256) {
        int m = e >> 6, d = e & 63;
        float o = 0.f;
        #pragma unroll
        for (int n = 0; n < 72; ++n) o += S[m][n] * VoT[d][n];
        int nq = mq * 18 + m;
        int i  = h * 9 + (nq >> 3);
        int jj = (nq & 7) * 64 + d;
        size_t oaddr;
        if (i < 8) oaddr = ((size_t)b * 513 * 8 + i) * 512 + jj;
        else       oaddr = OOUT_OFF + ((size_t)b * 64 + (i - 8)) * 512 + jj;
        out[oaddr] = o;
    }
}

extern "C" void kernel_launch(void* const* d_in, const int* in_sizes, int n_in,
                              void* d_out, int out_size, void* d_ws, size_t ws_size,
                              hipStream_t stream) {
    const float* temporal = (const float*)d_in[0];
    const float* others   = (const float*)d_in[1];
    const float* Wq = (const float*)d_in[2];
    const float* bq = (const float*)d_in[3];
    const float* Wk = (const float*)d_in[4];
    const float* bk = (const float*)d_in[5];
    const float* Wv = (const float*)d_in[6];
    const float* bv = (const float*)d_in[7];
    float* outp = (float*)d_out;
    u16* Qb = (u16*)d_ws;
    u16* Kb = Qb + (size_t)NR * D_;
    u16* Vb = Kb + (size_t)NR * D_;
    u16* Ab = Vb + (size_t)NR * D_;
    u16* Wb = Ab + (size_t)NRP * D_;
    const size_t need = ((size_t)3 * NR * D_ + (size_t)NRP * D_ + (size_t)1536 * D_) * 2;

    if (ws_size >= need) {
        hipLaunchKernelGGL(prep_4715, dim3((NRP + 1536) * 64 / 256), dim3(256), 0, stream,
                           temporal, others, Wq, Wk, Wv, Ab, Wb);
        hipLaunchKernelGGL(qkv_gemm2_4715, dim3(131 * 6), dim3(512), 0, stream,
                           Ab, Wb, bq, bk, bv, Qb, Kb, Vb);
    } else {
        hipLaunchKernelGGL(qkv_gemm_4715, dim3(261, 12), dim3(256), 0, stream,
                           temporal, others, Wq, bq, Wk, bk, Wv, bv, Qb, Kb, Vb);
    }
    hipLaunchKernelGGL(temporal_attn_4715, dim3(1024), dim3(256), 0, stream, Qb, Kb, Vb, outp);
    hipLaunchKernelGGL(others_attn_4715, dim3(256), dim3(256), 0, stream, Qb, Kb, Vb, outp);
}

// Round 4
// 365.391 us; speedup vs baseline: 1.1685x; 1.1685x over previous
//
#include <hip/hip_runtime.h>
#include <hip/hip_bf16.h>

typedef unsigned short u16;
typedef unsigned int   u32;
typedef short  s16x8 __attribute__((ext_vector_type(8)));
typedef __bf16 bf16x8 __attribute__((ext_vector_type(8)));
typedef float  f32x4 __attribute__((ext_vector_type(4)));

#define D_ 512
#define NR 33344          // B*L*M + B*72 = 32768 + 576
#define NRP 33792         // padded to 66*512 (block = 512 rows)
#define TROWS 32768       // temp rows
#define TOUT_OFF  0UL
#define OOUT_OFF  16809984UL
#define TATTN_OFF 17072128UL
#define OATTN_OFF 35946496UL

__device__ __forceinline__ float bf2f(u16 x) {
    union { u32 u; float f; } v; v.u = ((u32)x) << 16; return v.f;
}
__device__ __forceinline__ u16 f2bf(float f) {
    union { float f; u32 u; } v; v.f = f;
    u32 u = v.u;
    return (u16)((u + 0x7fffu + ((u >> 16) & 1u)) >> 16);
}
// load 8 contiguous fp32, round-to-nearest-even to bf16x8
__device__ __forceinline__ s16x8 cvt8(const float* p) {
    float4 a = *(const float4*)p;
    float4 b = *(const float4*)(p + 4);
    s16x8 r;
    r[0] = (short)f2bf(a.x); r[1] = (short)f2bf(a.y);
    r[2] = (short)f2bf(a.z); r[3] = (short)f2bf(a.w);
    r[4] = (short)f2bf(b.x); r[5] = (short)f2bf(b.y);
    r[6] = (short)f2bf(b.z); r[7] = (short)f2bf(b.w);
    return r;
}
__device__ __forceinline__ f32x4 mfma16(s16x8 a, s16x8 b, f32x4 c) {
    return __builtin_amdgcn_mfma_f32_16x16x32_bf16(
        __builtin_bit_cast(bf16x8, a), __builtin_bit_cast(bf16x8, b), c, 0, 0, 0);
}
__device__ __forceinline__ void gload_lds16(const u16* g, u16* l) {
    __builtin_amdgcn_global_load_lds(
        (const __attribute__((address_space(1))) void*)g,
        (__attribute__((address_space(3))) void*)l, 16, 0, 0);
}

// row r of the fused A matrix -> source row pointer (fp32)
__device__ __forceinline__ const float* a_src_row(int r, const float* temporal, const float* others) {
    if (r < TROWS) {
        int b = r >> 12;
        return temporal + (size_t)(r + 8 * (b + 1)) * D_;
    }
    int rr = r - TROWS;
    int b = rr / 72, j = rr - b * 72;
    return (j < 8) ? (temporal + (size_t)(b * 4104 + j) * D_)
                   : (others   + (size_t)(b * 64 + j - 8) * D_);
}

// ---------------- pre-pass: fp32 -> bf16, A in GEMM row order + W concat ----------------
__global__ __launch_bounds__(256) void prep_4715(
    const float* __restrict__ temporal, const float* __restrict__ others,
    const float* __restrict__ Wq, const float* __restrict__ Wk, const float* __restrict__ Wv,
    u16* __restrict__ Ab, u16* __restrict__ Wb)
{
    int idx = blockIdx.x * 256 + threadIdx.x;   // one thread = 8 floats
    int r  = idx >> 6;
    int ch = (idx & 63) * 8;
    if (r >= NRP + 1536) return;
    if (r < NRP) {
        u16* dst = Ab + (size_t)r * D_ + ch;
        if (r >= NR) {                           // zero pad rows
            u32* d32 = (u32*)dst;
            d32[0] = 0; d32[1] = 0; d32[2] = 0; d32[3] = 0;
            return;
        }
        *(s16x8*)dst = cvt8(a_src_row(r, temporal, others) + ch);
    } else {
        int n = r - NRP;
        const float* W = (n < 512) ? Wq : (n < 1024 ? Wk : Wv);
        *(s16x8*)(Wb + (size_t)n * D_ + ch) = cvt8(W + (size_t)(n & 511) * D_ + ch);
    }
}

// ---------------- QKV GEMM: resident-B-panel, barrier-free main loop ----------------
// N=1536, K=512: a 128-col B-panel is 128x512x2B = 128 KB = the whole LDS. Load it ONCE
// (XOR-swizzled global source -> linear gload_lds dest, rule #21), then each of 8 waves
// independently streams its 64 A-rows from global (L3-resident) straight into registers
// and runs the full K=512 against the resident panel. Zero barriers in the main loop ->
// no lockstep stalls; latency hidden by ILP. Epilogue stages the 64x128 output tile
// through the (dead) B-LDS to emit 256B-contiguous dwordx4 stores (kills the 4x HBM
// write amplification of the old scattered u16 epilogue).
__global__ __launch_bounds__(512, 2) void qkv_gemm2_4715(
    const u16* __restrict__ Ab, const u16* __restrict__ Wb,
    const float* __restrict__ bq, const float* __restrict__ bk, const float* __restrict__ bv,
    u16* __restrict__ Qb, u16* __restrict__ Kb, u16* __restrict__ Vb)
{
    __shared__ __align__(16) u16 Bs[128][512];    // 128 KB -> 1 block/CU, 8 waves
    const int tid  = threadIdx.x;
    const int lane = tid & 63;
    const int w    = tid >> 6;                    // 8 waves, each owns 64 rows

    // XCD swizzle: 792 blocks = 8 * 99 exactly -> simple bijective chunking.
    // Consecutive gx iterate nblk fastest: 12 consecutive work ids share one A m-group.
    int orig = blockIdx.x;
    int gx = (orig & 7) * 99 + (orig >> 3);
    const int nblk = gx % 12;
    const int mgrp = gx / 12;
    const int n0 = nblk * 128;
    const int mbase = mgrp * 512 + w * 64;

    // ---- stage B panel once: wave w loads rows w*16..w*16+15, one gload_lds per row ----
    // LDS[r][g] = global[r][(g&56) | ((g&7)^(r&7))]  (granule = 8 u16 = 16B)
    #pragma unroll
    for (int rr = 0; rr < 16; ++rr) {
        int r  = w * 16 + rr;
        int sg = (lane & 56) | ((lane & 7) ^ (r & 7));
        gload_lds16(Wb + (size_t)(n0 + r) * D_ + sg * 8, &Bs[r][0]);
    }
    asm volatile("s_waitcnt vmcnt(0)" ::: "memory");
    __syncthreads();

    const int fr = lane & 15;
    const int q  = lane >> 4;
    const u16* pa = Ab + (size_t)(mbase + fr) * D_ + q * 8;

    f32x4 acc[4][8];
    #pragma unroll
    for (int i = 0; i < 4; ++i)
        #pragma unroll
        for (int j = 0; j < 8; ++j) acc[i][j] = f32x4{0.f, 0.f, 0.f, 0.f};

    // ---- barrier-free K loop: 16 ksteps x (4 A-glb-loads + 8 B-lds-reads + 32 MFMA) ----
    #pragma unroll 4
    for (int ks = 0; ks < 16; ++ks) {
        const int g  = ks * 4 + q;
        const int pg = (g & 56) | ((g & 7) ^ (fr & 7));    // read-side of the B swizzle
        s16x8 a[4], bfr[8];
        #pragma unroll
        for (int mi = 0; mi < 4; ++mi)
            a[mi] = *(const s16x8*)(pa + (size_t)mi * 16 * D_ + ks * 32);
        #pragma unroll
        for (int nj = 0; nj < 8; ++nj)
            bfr[nj] = *(const s16x8*)&Bs[nj * 16 + fr][pg * 8];
        #pragma unroll
        for (int mi = 0; mi < 4; ++mi)
            #pragma unroll
            for (int nj = 0; nj < 8; ++nj)
                acc[mi][nj] = mfma16(a[mi], bfr[nj], acc[mi][nj]);
    }

    // ---- epilogue: wave-private LDS transpose -> coalesced 256B-row stores ----
    __syncthreads();                              // all waves done reading Bs
    u16* outp          = (nblk < 4) ? Qb : (nblk < 8 ? Kb : Vb);
    const float* biasp = (nblk < 4) ? bq : (nblk < 8 ? bk : bv);
    const int nn0 = n0 & 511;
    const int c = lane & 15;
    u16* ep = ((u16*)Bs) + w * 8192;              // wave-private [64][128] u16 = 16 KB

    float bias[8];
    #pragma unroll
    for (int nj = 0; nj < 8; ++nj) bias[nj] = biasp[nn0 + nj * 16 + c];

    #pragma unroll
    for (int mi = 0; mi < 4; ++mi)
        #pragma unroll
        for (int nj = 0; nj < 8; ++nj)
            #pragma unroll
            for (int p = 0; p < 4; ++p)
                ep[(mi * 16 + q * 4 + p) * 128 + nj * 16 + c] =
                    f2bf(acc[mi][nj][p] + bias[nj]);

    // read back linearly: 4 rows x 256B per instruction, store 16B/lane contiguous
    #pragma unroll
    for (int rr = 0; rr < 16; ++rr) {
        int rl = rr * 4 + q;
        s16x8 v = *(const s16x8*)&ep[rl * 128 + c * 8];
        int grow = mbase + rl;
        if (grow < NR)
            *(s16x8*)&outp[(size_t)grow * D_ + nn0 + c * 8] = v;
    }
}

// ---------------- fallback fused QKV GEMM (fp32 in, cvt in staging) ----------------
__global__ __launch_bounds__(256) void qkv_gemm_4715(
    const float* __restrict__ temporal, const float* __restrict__ others,
    const float* __restrict__ Wq, const float* __restrict__ bq,
    const float* __restrict__ Wk, const float* __restrict__ bk,
    const float* __restrict__ Wv, const float* __restrict__ bv,
    u16* __restrict__ Qb, u16* __restrict__ Kb, u16* __restrict__ Vb)
{
    __shared__ __align__(16) u16 As[128][72];
    __shared__ __align__(16) u16 Bs[128][72];
    const int tid  = threadIdx.x;
    const int lane = tid & 63;
    const int wave = tid >> 6;
    const int wr = wave >> 1, wc = wave & 1;
    const int m0 = blockIdx.x * 128;
    const int n0 = blockIdx.y * 128;

    const float* arow[4];
    #pragma unroll
    for (int i = 0; i < 4; ++i) {
        int r = m0 + (tid >> 3) + i * 32;
        if (r >= NR) r = 0;
        arow[i] = a_src_row(r, temporal, others);
    }
    const float* brow[4];
    #pragma unroll
    for (int i = 0; i < 4; ++i) {
        int n = n0 + (tid >> 3) + i * 32;
        const float* W = (n < 512) ? Wq : (n < 1024 ? Wk : Wv);
        brow[i] = W + (size_t)(n & 511) * D_;
    }
    const int acol = (tid & 7) * 8;
    const int srow = tid >> 3;

    f32x4 acc[4][4];
    #pragma unroll
    for (int i = 0; i < 4; ++i)
        #pragma unroll
        for (int j = 0; j < 4; ++j) acc[i][j] = f32x4{0.f, 0.f, 0.f, 0.f};

    for (int k0 = 0; k0 < 512; k0 += 64) {
        #pragma unroll
        for (int i = 0; i < 4; ++i) {
            *(s16x8*)&As[srow + i * 32][acol] = cvt8(arow[i] + k0 + acol);
            *(s16x8*)&Bs[srow + i * 32][acol] = cvt8(brow[i] + k0 + acol);
        }
        __syncthreads();
        #pragma unroll
        for (int kk = 0; kk < 64; kk += 32) {
            const int kc = kk + (lane >> 4) * 8;
            const int fr = lane & 15;
            s16x8 af[4], bfr[4];
            #pragma unroll
            for (int i = 0; i < 4; ++i) af[i]  = *(const s16x8*)&As[wr * 64 + i * 16 + fr][kc];
            #pragma unroll
            for (int j = 0; j < 4; ++j) bfr[j] = *(const s16x8*)&Bs[wc * 64 + j * 16 + fr][kc];
            #pragma unroll
            for (int i = 0; i < 4; ++i)
                #pragma unroll
                for (int j = 0; j < 4; ++j)
                    acc[i][j] = mfma16(af[i], bfr[j], acc[i][j]);
        }
        __syncthreads();
    }
    const int q = lane >> 4, c = lane & 15;
    #pragma unroll
    for (int j = 0; j < 4; ++j) {
        int n = n0 + wc * 64 + j * 16 + c;
        u16* outp          = (n < 512) ? Qb : (n < 1024 ? Kb : Vb);
        const float* biasp = (n < 512) ? bq : (n < 1024 ? bk : bv);
        int nn = n & 511;
        float bias = biasp[nn];
        #pragma unroll
        for (int i = 0; i < 4; ++i) {
            int rb = m0 + wr * 64 + i * 16 + q * 4;
            #pragma unroll
            for (int p = 0; p < 4; ++p) {
                int r = rb + p;
                if (r < NR) outp[(size_t)r * D_ + nn] = f2bf(acc[i][j][p] + bias);
            }
        }
    }
}

// ---------------- temporal attention (MFMA, M padded 8->16, N padded 72->80/96) ----------------
__global__ __launch_bounds__(256) void temporal_attn_4715(
    const u16* __restrict__ Qb, const u16* __restrict__ Kb, const u16* __restrict__ Vb,
    float* __restrict__ out)
{
    const int blk = blockIdx.x;           // ((b*4 + hp)*32 + lc)
    const int lc = blk & 31;
    const int hp = (blk >> 5) & 3;
    const int b  = blk >> 7;
    const int tid = threadIdx.x, lane = tid & 63, w = tid >> 6;
    const int q = lane >> 4, c = lane & 15;

    __shared__ __align__(16) u16 KtsS[2][64][72];   // cross-wave, written once
    __shared__ __align__(16) u16 VtsS[2][64][96];   // cross-wave, written once
    __shared__ __align__(16) u16 KttW[4][8][72];    // wave-private
    __shared__ __align__(16) u16 VttW[4][64][8];    // wave-private
    __shared__ __align__(16) u16 Pw[4][16][104];    // wave-private (pad cols written once)

    const size_t srowbase = (size_t)TROWS + (size_t)b * 72 + 8;
    for (int cch = tid; cch < 1024; cch += 256) {
        int hh = cch >> 9;
        int o  = (cch >> 3) & 63;
        int d8 = (cch & 7) * 8;
        int hbase = (hp * 2 + hh) * 64;
        *(s16x8*)&KtsS[hh][o][d8] = *(const s16x8*)&Kb[(srowbase + o) * D_ + hbase + d8];
        s16x8 vv = *(const s16x8*)&Vb[(srowbase + o) * D_ + hbase + d8];
        #pragma unroll
        for (int jj = 0; jj < 8; ++jj) VtsS[hh][d8 + jj][8 + o] = (u16)vv[jj];
    }
    for (int z = tid; z < 2 * 64 * 24; z += 256) {
        int hh = z / (64 * 24); int rem = z - hh * 64 * 24;
        VtsS[hh][rem / 24][72 + rem % 24] = 0;
    }
    for (int z = tid; z < 4 * 16 * 24; z += 256) {
        int ww = z / (16 * 24); int rem = z - ww * 16 * 24;
        Pw[ww][rem / 24][80 + rem % 24] = 0;
    }
    __syncthreads();    // the ONLY barrier: everything below is wave-private

    const float scale = 0.125f;
    for (int ti = 0; ti < 8; ++ti) {
        const int tsk = w + 4 * ti;               // 0..31
        const int hh = tsk >> 4;
        const int il = tsk & 15;
        const int l  = lc * 16 + il;
        const int h  = hp * 2 + hh;
        const int hbase = h * 64;
        const size_t rbase = ((size_t)b * 512 + l) * 8;

        { // stage Ktt (8x64) for this wave
            int m = lane >> 3, d8 = (lane & 7) * 8;
            *(s16x8*)&KttW[w][m][d8] = *(const s16x8*)&Kb[(rbase + m) * D_ + hbase + d8];
        }
        { // stage Vtt^T (64 x 8)
            #pragma unroll
            for (int m = 0; m < 8; ++m)
                VttW[w][lane][m] = Vb[(rbase + m) * D_ + hbase + lane];
        }
        const int mq = (c < 8) ? c : (c - 8);
        s16x8 aq0 = *(const s16x8*)&Qb[(rbase + mq) * D_ + hbase + q * 8];
        s16x8 aq1 = *(const s16x8*)&Qb[(rbase + mq) * D_ + hbase + 32 + q * 8];
        asm volatile("s_waitcnt lgkmcnt(0)" ::: "memory");  // in-wave RAW on KttW/VttW

        // QK^T: 5 n-tiles of 16, k = 64 (2 steps)
        f32x4 sacc[5];
        #pragma unroll
        for (int j = 0; j < 5; ++j) sacc[j] = f32x4{0.f, 0.f, 0.f, 0.f};
        #pragma unroll
        for (int j = 0; j < 5; ++j) {
            int g = j * 16 + c;
            const u16* kp0;
            if (g < 8) kp0 = &KttW[w][g][0];
            else { int o = g - 8; if (o > 63) o = 63; kp0 = &KtsS[hh][o][0]; }
            s16x8 b0 = *(const s16x8*)(kp0 + q * 8);
            s16x8 b1 = *(const s16x8*)(kp0 + 32 + q * 8);
            sacc[j] = mfma16(aq0, b0, sacc[j]);
            sacc[j] = mfma16(aq1, b1, sacc[j]);
        }
        float ev[5][4];
        float mx[4] = {-1e30f, -1e30f, -1e30f, -1e30f};
        #pragma unroll
        for (int j = 0; j < 5; ++j) {
            bool valid = (j < 4) || (c < 8);
            #pragma unroll
            for (int p = 0; p < 4; ++p) {
                float v = sacc[j][p] * scale;
                ev[j][p] = valid ? v : -1e30f;
                if (valid) mx[p] = fmaxf(mx[p], v);
            }
        }
        #pragma unroll
        for (int msk = 1; msk < 16; msk <<= 1)
            #pragma unroll
            for (int p = 0; p < 4; ++p)
                mx[p] = fmaxf(mx[p], __shfl_xor(mx[p], msk, 16));
        float sm[4] = {0.f, 0.f, 0.f, 0.f};
        #pragma unroll
        for (int j = 0; j < 5; ++j) {
            bool valid = (j < 4) || (c < 8);
            #pragma unroll
            for (int p = 0; p < 4; ++p) {
                float e = valid ? __expf(ev[j][p] - mx[p]) : 0.f;
                ev[j][p] = e;
                sm[p] += e;
            }
        }
        #pragma unroll
        for (int msk = 1; msk < 16; msk <<= 1)
            #pragma unroll
            for (int p = 0; p < 4; ++p)
                sm[p] += __shfl_xor(sm[p], msk, 16);
        float inv[4];
        #pragma unroll
        for (int p = 0; p < 4; ++p) inv[p] = 1.0f / sm[p];

        float* attnp = out + TATTN_OFF + ((((size_t)b * 8 + h) * 512 + l) * 8) * 72;
        #pragma unroll
        for (int j = 0; j < 5; ++j) {
            #pragma unroll
            for (int p = 0; p < 4; ++p) {
                int row = q * 4 + p;
                int col = j * 16 + c;
                float pv = ev[j][p] * inv[p];
                Pw[w][row][col] = f2bf(pv);
                if (row < 8 && col < 72)
                    attnp[(size_t)row * 72 + col] = pv;
            }
        }
        asm volatile("s_waitcnt lgkmcnt(0)" ::: "memory");  // in-wave RAW on Pw

        f32x4 oacc[4];
        #pragma unroll
        for (int j = 0; j < 4; ++j) oacc[j] = f32x4{0.f, 0.f, 0.f, 0.f};
        #pragma unroll
        for (int ks = 0; ks < 3; ++ks) {
            s16x8 ap = *(const s16x8*)&Pw[w][c][ks * 32 + q * 8];
            #pragma unroll
            for (int j = 0; j < 4; ++j) {
                int d = j * 16 + c;
                int kb = ks * 32 + q * 8;
                const u16* vp = (kb == 0) ? &VttW[w][d][0] : &VtsS[hh][d][kb];
                s16x8 bp = *(const s16x8*)vp;
                oacc[j] = mfma16(ap, bp, oacc[j]);
            }
        }
        float* toutp = out + (((size_t)b * 513 + l + 1) * 8) * 512 + hbase;
        #pragma unroll
        for (int j = 0; j < 4; ++j) {
            int d = j * 16 + c;
            #pragma unroll
            for (int p = 0; p < 4; ++p) {
                int row = q * 4 + p;
                if (row < 8)
                    toutp[(size_t)row * 512 + d] = oacc[j][p];
            }
        }
    }
}

// ---------------- others (ss) attention ----------------
__global__ __launch_bounds__(256) void others_attn_4715(
    const u16* __restrict__ Qb, const u16* __restrict__ Kb, const u16* __restrict__ Vb,
    float* __restrict__ out)
{
    const int blk = blockIdx.x;       // ((b*8 + h)*4 + mq)
    const int mq = blk & 3;
    const int h  = (blk >> 2) & 7;
    const int b  = blk >> 5;
    const int tid = threadIdx.x;
    const int hbase = h * 64;
    const size_t rbase = (size_t)TROWS + (size_t)b * 72;

    __shared__ float Qo[18][68];
    __shared__ float Ko[72][68];
    __shared__ float VoT[64][84];
    __shared__ float S[18][80];

    for (int e = tid; e < 72 * 64; e += 256) {
        int r = e >> 6, d = e & 63;
        Ko[r][d]  = bf2f(Kb[(rbase + r) * D_ + hbase + d]);
        VoT[d][r] = bf2f(Vb[(rbase + r) * D_ + hbase + d]);
    }
    for (int e = tid; e < 18 * 64; e += 256) {
        int r = e >> 6, d = e & 63;
        Qo[r][d] = bf2f(Qb[(rbase + mq * 18 + r) * D_ + hbase + d]);
    }
    for (int e = tid; e < 64 * 12; e += 256) VoT[e / 12][72 + e % 12] = 0.f;
    __syncthreads();

    for (int e = tid; e < 18 * 72; e += 256) {
        int m = e / 72, n = e - m * 72;
        const float* qp = Qo[m];
        const float* kp = Ko[n];
        float s = 0.f;
        #pragma unroll
        for (int d = 0; d < 64; ++d) s += qp[d] * kp[d];
        S[m][n] = s * 0.125f;
    }
    __syncthreads();
    if (tid < 18) {
        int m = tid;
        float mx = -1e30f;
        for (int n = 0; n < 72; ++n) mx = fmaxf(mx, S[m][n]);
        float sm = 0.f;
        for (int n = 0; n < 72; ++n) { float e = __expf(S[m][n] - mx); S[m][n] = e; sm += e; }
        float inv = 1.f / sm;
        size_t arow = OATTN_OFF + (((size_t)b * 8 + h) * 72 + (mq * 18 + m)) * 72;
        for (int n = 0; n < 72; ++n) {
            float p = S[m][n] * inv; S[m][n] = p;
            out[arow + n] = p;
        }
    }
    __syncthreads();
    // others_ = others.reshape(B,-1,D), no transpose: (h,n,d) -> i=h*9+n/8, j=(n%8)*64+d
    for (int e = tid; e < 18 * 64; e += 256) {
        int m = e >> 6, d = e & 63;
        float o = 0.f;
        #pragma unroll
        for (int n = 0; n < 72; ++n) o += S[m][n] * VoT[d][n];
        int nq = mq * 18 + m;
        int i  = h * 9 + (nq >> 3);
        int jj = (nq & 7) * 64 + d;
        size_t oaddr;
        if (i < 8) oaddr = ((size_t)b * 513 * 8 + i) * 512 + jj;
        else       oaddr = OOUT_OFF + ((size_t)b * 64 + (i - 8)) * 512 + jj;
        out[oaddr] = o;
    }
}

extern "C" void kernel_launch(void* const* d_in, const int* in_sizes, int n_in,
                              void* d_out, int out_size, void* d_ws, size_t ws_size,
                              hipStream_t stream) {
    const float* temporal = (const float*)d_in[0];
    const float* others   = (const float*)d_in[1];
    const float* Wq = (const float*)d_in[2];
    const float* bq = (const float*)d_in[3];
    const float* Wk = (const float*)d_in[4];
    const float* bk = (const float*)d_in[5];
    const float* Wv = (const float*)d_in[6];
    const float* bv = (const float*)d_in[7];
    float* outp = (float*)d_out;
    u16* Qb = (u16*)d_ws;
    u16* Kb = Qb + (size_t)NR * D_;
    u16* Vb = Kb + (size_t)NR * D_;
    u16* Ab = Vb + (size_t)NR * D_;
    u16* Wb = Ab + (size_t)NRP * D_;
    const size_t need = ((size_t)3 * NR * D_ + (size_t)NRP * D_ + (size_t)1536 * D_) * 2;

    if (ws_size >= need) {
        hipLaunchKernelGGL(prep_4715, dim3((NRP + 1536) * 64 / 256), dim3(256), 0, stream,
                           temporal, others, Wq, Wk, Wv, Ab, Wb);
        hipLaunchKernelGGL(qkv_gemm2_4715, dim3(66 * 12), dim3(512), 0, stream,
                           Ab, Wb, bq, bk, bv, Qb, Kb, Vb);
    } else {
        hipLaunchKernelGGL(qkv_gemm_4715, dim3(261, 12), dim3(256), 0, stream,
                           temporal, others, Wq, bq, Wk, bk, Wv, bv, Qb, Kb, Vb);
    }
    hipLaunchKernelGGL(temporal_attn_4715, dim3(1024), dim3(256), 0, stream, Qb, Kb, Vb, outp);
    hipLaunchKernelGGL(others_attn_4715, dim3(256), dim3(256), 0, stream, Qb, Kb, Vb, outp);
}